// Round 7
// baseline (838.886 us; speedup 1.0000x reference)
//
#include <hip/hip_runtime.h>

// ---------------------------------------------------------------------------
// GraphSAGE layer — ROUND 7. Single __global__ symbol (harness constraint),
// fp32 I/O, bf16 MFMA core, bitmask-compressed adjacency.
//
// dispatch 0 (phase 0, 9474 blocks, dyn-LDS 9216 B):
//   blocks [0,8192):    bits[row] = ballot(adj[row]>0) (8 MB), invdeg[row]
//   blocks [8192,9216): x fp32 -> xT bf16 [512][8192] (64x64 LDS transpose)
//   blocks [9216,9474): Wt = (W_self@Wc1 | W_nb@Wc2) bf16 [512][1024];
//                       cbias = b_self@Wc1 + b_nb@Wc2 + b_comb (fp32)
// dispatch 1 (phase 1, grid (4,128), dyn-LDS 50176 B):
//   agg = mask@x * invdeg   BM=64 BN=128 BK=128, A unpacked from bits in VALU
// dispatch 2 (phase 2, grid (4,128), dyn-LDS 24576 B):
//   out = relu([x|agg] @ Wt^T + cbias), K=1024, x converted during staging
// ---------------------------------------------------------------------------

using short8 = __attribute__((ext_vector_type(8))) short;   // 8 bf16 (4 VGPRs)
using f32x4  = __attribute__((ext_vector_type(4))) float;   // MFMA acc

typedef unsigned short U16;
typedef unsigned int   U32;
typedef unsigned long long U64;

__device__ __forceinline__ U16 f2bf(float f) {
  U32 u = __float_as_uint(f);
  u = (u + 0x7fffu + ((u >> 16) & 1u)) >> 16;   // RNE
  return (U16)u;
}
__device__ __forceinline__ U32 pack2bf(float a, float b) {
  return (U32)f2bf(a) | ((U32)f2bf(b) << 16);
}

__global__ void GraphSAGELayer_773094114149_kernel(
    int phase,
    const float* __restrict__ x,     const int* __restrict__ adj,
    const float* __restrict__ Wself, const float* __restrict__ bself,
    const float* __restrict__ Wnb,   const float* __restrict__ bnb,
    const float* __restrict__ Wcomb, const float* __restrict__ bcomb,
    U16* __restrict__ xT, U16* __restrict__ aggp, U64* __restrict__ bits,
    float* __restrict__ invdeg, U16* __restrict__ Wt,
    float* __restrict__ cbias, float* __restrict__ outp)
{
  extern __shared__ __align__(16) unsigned char smem[];
  const int tid = threadIdx.x;

  // =========================================================================
  // phase 0: prep (bits+deg | transpose | fused weights)
  // =========================================================================
  if (phase == 0) {
    if (blockIdx.x < 8192) {
      // ---- adjacency -> bitmask + degree. One row per block, quarter/wave.
      const int row = blockIdx.x;
      const int wv = tid >> 6, ln = tid & 63;
      const int* arow = adj + (size_t)row * 8192 + wv * 2048;
      U64* brow = bits + (size_t)row * 128 + wv * 32;
      float* sdeg = (float*)smem;
      int dsum = 0;
#pragma unroll 4
      for (int p = 0; p < 32; ++p) {
        int v = arow[p * 64 + ln];
        U64 mask = __ballot(v > 0);
        dsum += (int)__popcll(mask);
        if (ln == 0) brow[p] = mask;
      }
      if (ln == 0) sdeg[wv] = (float)dsum;
      __syncthreads();
      if (tid == 0)
        invdeg[row] = 1.0f / fmaxf(sdeg[0] + sdeg[1] + sdeg[2] + sdeg[3], 1.0f);
      return;
    }
    if (blockIdx.x < 9216) {
      // ---- x fp32 -> xT bf16 (64x64 tiles via LDS)
      const int b = blockIdx.x - 8192;
      const int n0 = (b & 7) * 64;
      const int m0 = (b >> 3) * 64;
      U16* tl = (U16*)smem;                     // [64][72] (144 B rows)
      const int r  = tid >> 2;
      const int cq = (tid & 3) * 16;
      const float* src = x + (size_t)(m0 + r) * 512 + n0 + cq;
      U32 pk[8];
#pragma unroll
      for (int i = 0; i < 8; ++i) {
        float2 f = *(const float2*)(src + 2 * i);
        pk[i] = pack2bf(f.x, f.y);
      }
#pragma unroll
      for (int i = 0; i < 8; ++i) {
        tl[(cq + 2*i)     * 72 + r] = (U16)(pk[i] & 0xffffu);
        tl[(cq + 2*i + 1) * 72 + r] = (U16)(pk[i] >> 16);
      }
      __syncthreads();
      const int c2 = tid >> 2;
      const int mq = (tid & 3) * 16;
      uint4 o0 = *(const uint4*)&tl[c2 * 72 + mq];
      uint4 o1 = *(const uint4*)&tl[c2 * 72 + mq + 8];
      U16* dT = xT + (size_t)(n0 + c2) * 8192 + m0 + mq;
      *(uint4*)dT       = o0;
      *(uint4*)(dT + 8) = o1;
      return;
    }
    // ---- fused weights + bias
    {
      const int b = blockIdx.x - 9216;          // 0..257
      if (b >= 256) {
        int n = (b - 256) * 256 + tid;
        float acc = bcomb[n];
        for (int j = 0; j < 512; ++j) {
          acc += bself[j] * Wcomb[(size_t)j * 512 + n];
          acc += bnb[j]   * Wcomb[(size_t)(512 + j) * 512 + n];
        }
        cbias[n] = acc;
        return;
      }
      const int half = b >> 7;
      const int k0   = (b & 127) * 4;
      const float* Wsrc = half ? Wnb : Wself;
      const int woff = half * 512;
      float* wsf = (float*)smem;                // [4][512]
      {
        int idx = tid * 8;
        *(float4*)&wsf[idx]     = *(const float4*)&Wsrc[(size_t)(k0 + (idx >> 9)) * 512 + (idx & 511)];
        *(float4*)&wsf[idx + 4] = *(const float4*)&Wsrc[(size_t)(k0 + ((idx+4) >> 9)) * 512 + ((idx+4) & 511)];
      }
      __syncthreads();
      float a[8] = {0,0,0,0,0,0,0,0};
      for (int j = 0; j < 512; ++j) {
        float wc0 = Wcomb[(size_t)(woff + j) * 512 + tid];
        float wc1 = Wcomb[(size_t)(woff + j) * 512 + tid + 256];
        float s0 = wsf[j], s1 = wsf[512 + j], s2 = wsf[1024 + j], s3 = wsf[1536 + j];
        a[0] += s0 * wc0;  a[4] += s0 * wc1;
        a[1] += s1 * wc0;  a[5] += s1 * wc1;
        a[2] += s2 * wc0;  a[6] += s2 * wc1;
        a[3] += s3 * wc0;  a[7] += s3 * wc1;
      }
      U16* w0 = Wt + (size_t)tid * 1024 + woff + k0;
      U16* w1 = Wt + (size_t)(tid + 256) * 1024 + woff + k0;
      for (int q = 0; q < 4; ++q) { w0[q] = f2bf(a[q]); w1[q] = f2bf(a[4 + q]); }
      return;
    }
  }

  // ---- common MFMA-phase lane decomposition ----
  const int lane = tid & 63;
  const int wave = tid >> 6;
  const int quad = lane >> 4;
  const int wm = (wave & 1) * 32;
  const int wn = (wave >> 1) * 64;
  const int nBase = blockIdx.x * 128;
  const int mBase = blockIdx.y * 64;

  // =========================================================================
  // phase 1: agg = mask@x * invdeg. grid (4,128). BM=64 BN=128 BK=128.
  // A: 32 bits/thread/iter from bitmask, VALU-unpacked to bf16 LDS (272B rows)
  // B: xT 128B/thread/iter, XOR-chunk-swizzled LDS (256B rows, 16B chunks)
  // =========================================================================
  if (phase == 1) {
    U16* Aa = (U16*)smem;                       // [64][136] u16 (272 B rows)
    U16* Bb = (U16*)(smem + 17408);             // [128][128] u16 (256 B rows)
    const U32* bits32 = (const U32*)bits;

    const int r  = tid >> 2;
    const int qt = tid & 3;
    const U32* abase = bits32 + (size_t)(mBase + r) * 256 + qt;
    U16* awr = Aa + r * 136 + qt * 32;

    const U16* bgp[8]; U16* blp[8];
#pragma unroll
    for (int i = 0; i < 8; ++i) {
      int c  = i * 256 + tid;
      int nr = c >> 4;
      int gk = c & 15;
      bgp[i] = xT + (size_t)(nBase + nr) * 8192 + gk * 8;
      blp[i] = Bb + nr * 128 + ((gk ^ (nr & 15)) * 8);
    }

    f32x4 acc[2][4];
#pragma unroll
    for (int a = 0; a < 2; ++a)
#pragma unroll
      for (int b = 0; b < 4; ++b) acc[a][b] = (f32x4){0.f, 0.f, 0.f, 0.f};

    U32 abits = abase[0];
    uint4 bv[8];
#pragma unroll
    for (int i = 0; i < 8; ++i) bv[i] = *(const uint4*)(bgp[i]);

    for (int it = 0; it < 64; ++it) {
      __syncthreads();   // previous tile fully consumed

#pragma unroll
      for (int i = 0; i < 8; ++i) *(uint4*)blp[i] = bv[i];

      // unpack 32 adjacency bits -> 32 bf16 {0,1.0} (16 packed u32)
      U32 o[16];
#pragma unroll
      for (int j = 0; j < 16; ++j) {
        U32 t2 = (abits >> (2 * j)) & 3u;
        o[j] = ((t2 | (t2 << 15)) & 0x10001u) * 0x3F80u;
      }
      *(uint4*)(awr)      = make_uint4(o[0],  o[1],  o[2],  o[3]);
      *(uint4*)(awr + 8)  = make_uint4(o[4],  o[5],  o[6],  o[7]);
      *(uint4*)(awr + 16) = make_uint4(o[8],  o[9],  o[10], o[11]);
      *(uint4*)(awr + 24) = make_uint4(o[12], o[13], o[14], o[15]);

      __syncthreads();   // tile ready

      if (it + 1 < 64) {
        const int k1 = (it + 1) * 128;
        abits = abase[(it + 1) * 4];
#pragma unroll
        for (int i = 0; i < 8; ++i) bv[i] = *(const uint4*)(bgp[i] + k1);
      }

#pragma unroll
      for (int s = 0; s < 4; ++s) {
        short8 af[2], bfr[4];
        const int kb = s * 64 + quad * 16;
#pragma unroll
        for (int tm = 0; tm < 2; ++tm) {
          int m = wm + tm * 16 + (lane & 15);
          af[tm] = *(const short8*)((const char*)Aa + m * 272 + kb);
        }
        const int g = s * 4 + quad;
#pragma unroll
        for (int tn = 0; tn < 4; ++tn) {
          int n = wn + tn * 16 + (lane & 15);
          bfr[tn] = *(const short8*)((const char*)Bb + n * 256 + ((g ^ (n & 15)) * 16));
        }
#pragma unroll
        for (int tm = 0; tm < 2; ++tm)
#pragma unroll
          for (int tn = 0; tn < 4; ++tn)
            acc[tm][tn] = __builtin_amdgcn_mfma_f32_16x16x32_bf16(
                af[tm], bfr[tn], acc[tm][tn], 0, 0, 0);
      }
    }

#pragma unroll
    for (int tm = 0; tm < 2; ++tm) {
      int rb = wm + tm * 16 + quad * 4;
#pragma unroll
      for (int rr = 0; rr < 4; ++rr) {
        float inv = invdeg[mBase + rb + rr];
#pragma unroll
        for (int tn = 0; tn < 4; ++tn) {
          int n = nBase + wn + tn * 16 + (lane & 15);
          aggp[(size_t)(mBase + rb + rr) * 512 + n] = f2bf(acc[tm][tn][rr] * inv);
        }
      }
    }
    return;
  }

  // =========================================================================
  // phase 2: out = relu([x|agg] @ Wt^T + cbias). grid (4,128). K=1024, BK=64.
  // A from x (fp32, packed during staging) for it<8, from aggp (bf16) after.
  // =========================================================================
  {
    U16* As2 = (U16*)smem;                      // [64][64]  (128 B rows)
    U16* Bs2 = (U16*)(smem + 8192);             // [128][64] (128 B rows)

    int amr[2], agc[2]; U16* alp[2];
#pragma unroll
    for (int i = 0; i < 2; ++i) {
      int c  = i * 256 + tid;
      amr[i] = c >> 3;
      agc[i] = c & 7;
      alp[i] = As2 + amr[i] * 64 + ((agc[i] ^ (amr[i] & 7)) * 8);
    }
    const U16* bgp[4]; U16* blp[4];
#pragma unroll
    for (int i = 0; i < 4; ++i) {
      int c  = i * 256 + tid;
      int nr = c >> 3;
      int gc = c & 7;
      bgp[i] = Wt + (size_t)(nBase + nr) * 1024 + gc * 8;
      blp[i] = Bs2 + nr * 64 + ((gc ^ (nr & 7)) * 8);
    }

    f32x4 acc[2][4];
#pragma unroll
    for (int a = 0; a < 2; ++a)
#pragma unroll
      for (int b = 0; b < 4; ++b) acc[a][b] = (f32x4){0.f, 0.f, 0.f, 0.f};

    uint4 av[2], bv[4];
    // prologue it=0 (A from x fp32)
#pragma unroll
    for (int i = 0; i < 2; ++i) {
      const float* ap = x + (size_t)(mBase + amr[i]) * 512 + agc[i] * 8;
      float4 f0 = *(const float4*)ap;
      float4 f1 = *(const float4*)(ap + 4);
      av[i] = make_uint4(pack2bf(f0.x,f0.y), pack2bf(f0.z,f0.w),
                         pack2bf(f1.x,f1.y), pack2bf(f1.z,f1.w));
    }
#pragma unroll
    for (int i = 0; i < 4; ++i) bv[i] = *(const uint4*)(bgp[i]);

    for (int it = 0; it < 16; ++it) {
      __syncthreads();
#pragma unroll
      for (int i = 0; i < 2; ++i) *(uint4*)alp[i] = av[i];
#pragma unroll
      for (int i = 0; i < 4; ++i) *(uint4*)blp[i] = bv[i];
      __syncthreads();

      if (it + 1 < 16) {
        const int it1 = it + 1;
        if (it1 < 8) {
#pragma unroll
          for (int i = 0; i < 2; ++i) {
            const float* ap = x + (size_t)(mBase + amr[i]) * 512 + it1 * 64 + agc[i] * 8;
            float4 f0 = *(const float4*)ap;
            float4 f1 = *(const float4*)(ap + 4);
            av[i] = make_uint4(pack2bf(f0.x,f0.y), pack2bf(f0.z,f0.w),
                               pack2bf(f1.x,f1.y), pack2bf(f1.z,f1.w));
          }
        } else {
#pragma unroll
          for (int i = 0; i < 2; ++i)
            av[i] = *(const uint4*)(aggp + (size_t)(mBase + amr[i]) * 512 +
                                    (it1 - 8) * 64 + agc[i] * 8);
        }
#pragma unroll
        for (int i = 0; i < 4; ++i) bv[i] = *(const uint4*)(bgp[i] + it1 * 64);
      }

#pragma unroll
      for (int s = 0; s < 2; ++s) {
        short8 af[2], bfr[4];
        const int g = s * 4 + quad;
#pragma unroll
        for (int tm = 0; tm < 2; ++tm) {
          int m = wm + tm * 16 + (lane & 15);
          af[tm] = *(const short8*)((const char*)As2 + m * 128 + ((g ^ (m & 7)) * 16));
        }
#pragma unroll
        for (int tn = 0; tn < 4; ++tn) {
          int n = wn + tn * 16 + (lane & 15);
          bfr[tn] = *(const short8*)((const char*)Bs2 + n * 128 + ((g ^ (n & 7)) * 16));
        }
#pragma unroll
        for (int tm = 0; tm < 2; ++tm)
#pragma unroll
          for (int tn = 0; tn < 4; ++tn)
            acc[tm][tn] = __builtin_amdgcn_mfma_f32_16x16x32_bf16(
                af[tm], bfr[tn], acc[tm][tn], 0, 0, 0);
      }
    }

    float bias[4];
#pragma unroll
    for (int tn = 0; tn < 4; ++tn)
      bias[tn] = cbias[nBase + wn + tn * 16 + (lane & 15)];

#pragma unroll
    for (int tm = 0; tm < 2; ++tm) {
      int rb = wm + tm * 16 + quad * 4;
#pragma unroll
      for (int tn = 0; tn < 4; ++tn) {
        int n = nBase + wn + tn * 16 + (lane & 15);
#pragma unroll
        for (int rr = 0; rr < 4; ++rr) {
          float v = fmaxf(acc[tm][tn][rr] + bias[tn], 0.0f);
          outp[(size_t)(mBase + rb + rr) * 512 + n] = v;
        }
      }
    }
  }
}

// ---------------------------------------------------------------------------
extern "C" void kernel_launch(void* const* d_in, const int* in_sizes, int n_in,
                              void* d_out, int out_size, void* d_ws, size_t ws_size,
                              hipStream_t stream) {
  (void)in_sizes; (void)n_in; (void)out_size; (void)ws_size;

  const float* x     = (const float*)d_in[0];
  const int*   adj   = (const int*)d_in[1];
  const float* Wself = (const float*)d_in[2];
  const float* bself = (const float*)d_in[3];
  const float* Wnb   = (const float*)d_in[4];
  const float* bnb   = (const float*)d_in[5];
  const float* Wcomb = (const float*)d_in[6];
  const float* bcomb = (const float*)d_in[7];
  float* out = (float*)d_out;

  char* ws = (char*)d_ws;
  U16*   xT     = (U16*)(ws);                   // 8 MB  [512][8192] bf16
  U16*   aggp   = (U16*)(ws + 8388608);         // 8 MB  [8192][512] bf16
  U64*   bits   = (U64*)(ws + 16777216);        // 8 MB  [8192][128] u64
  U16*   Wt     = (U16*)(ws + 25165824);        // 1 MB  [512][1024] bf16
  float* cbias  = (float*)(ws + 26214400);      // 2 KB
  float* invdeg = (float*)(ws + 26216448);      // 32 KB

#define ARGS(P) (P), x, adj, Wself, bself, Wnb, bnb, Wcomb, bcomb, \
                xT, aggp, bits, invdeg, Wt, cbias, out
  GraphSAGELayer_773094114149_kernel<<<dim3(9474),   256,  9216, stream>>>(ARGS(0));
  GraphSAGELayer_773094114149_kernel<<<dim3(4, 128), 256, 50176, stream>>>(ARGS(1));
  GraphSAGELayer_773094114149_kernel<<<dim3(4, 128), 256, 24576, stream>>>(ARGS(2));
#undef ARGS
}